// Round 7
// baseline (195.682 us; speedup 1.0000x reference)
//
#include <hip/hip_runtime.h>

#define NNODES 50000
#define FEAT 256
#define NH 8
#define DHEAD 32
#define DEG 16
#define CDIM 256  // NH*DHEAD

typedef __attribute__((ext_vector_type(4))) float floatx4;
typedef __attribute__((ext_vector_type(8))) short shortx8;

__device__ __forceinline__ unsigned short f2bf(float f) {
  union { float f; unsigned u; } v; v.f = f;
  unsigned r = v.u + 0x7fffu + ((v.u >> 16) & 1u);  // RN-even
  return (unsigned short)(r >> 16);
}
__device__ __forceinline__ float bf2f(unsigned short b) {
  union { unsigned u; float f; } v; v.u = ((unsigned)b) << 16;
  return v.f;
}

// Kernel 0: build Wt2 (17 MFMA B-tiles, fragment-major) + sbias.
// Tiles 0..15: Wt2[((cgrp*8+kt)*64+lane)*8+jj] = W for (c = cgrp*16+(lane&15),
//   k = kt*32+(lane>>4)*8+jj). Tile 16 (extra cols 256..271): col 256+j is
//   (W·a_src)[k][j] for j<8, (W·a_dst)[k][j-8] for j>=8 — so the GEMM emits
//   s1/s2 directly. sbias[j] = bW[h]·a_src[h] (j<8) / bW[h]·a_dst[h]+a_bias
//   (j>=8). Blocks 0..63 normal, 64..67 extra tile, 68 sbias.
__global__ __launch_bounds__(256) void convert_wt(
    const float* __restrict__ W, const float* __restrict__ bW,
    const float* __restrict__ a_src, const float* __restrict__ a_dst,
    const float* __restrict__ a_bias, unsigned short* __restrict__ Wt2,
    float* __restrict__ sbias) {
  int b = blockIdx.x;
  if (b < 64) {
    int t = b * 256 + threadIdx.x;
#pragma unroll
    for (int p = 0; p < 4; ++p) {
      int idx = t * 4 + p;  // [0, 65536)
      int jj = idx & 7;
      int l = (idx >> 3) & 63;
      int kt = (idx >> 9) & 7;
      int cgrp = idx >> 12;
      int c = cgrp * 16 + (l & 15);
      int f = kt * 32 + ((l >> 4) << 3) + jj;
      Wt2[idx] = f2bf(W[(size_t)(c >> 5) * (FEAT * DHEAD) + (size_t)f * DHEAD + (c & 31)]);
    }
  } else if (b < 68) {
    int t = (b - 64) * 256 + threadIdx.x;  // [0,1024)
#pragma unroll
    for (int p = 0; p < 4; ++p) {
      int idx = t * 4 + p;  // [0, 4096)
      int jj = idx & 7;
      int l = (idx >> 3) & 63;
      int kt = idx >> 9;
      int cp = l & 15;  // extra col 256+cp
      int k = kt * 32 + ((l >> 4) << 3) + jj;
      int hd = cp & 7;
      const float* vec = (cp < 8) ? (a_src + hd * DHEAD) : (a_dst + hd * DHEAD);
      const float* wr = W + (size_t)hd * (FEAT * DHEAD) + (size_t)k * DHEAD;
      float acc = 0.f;
#pragma unroll
      for (int d = 0; d < DHEAD; ++d) acc += wr[d] * vec[d];
      Wt2[16 * 4096 + idx] = f2bf(acc);
    }
  } else {
    int j = threadIdx.x;
    if (j < 16) {
      int hd = j & 7;
      const float* vec = (j < 8) ? (a_src + hd * DHEAD) : (a_dst + hd * DHEAD);
      float acc = (j < 8) ? 0.f : a_bias[hd];
#pragma unroll
      for (int d = 0; d < DHEAD; ++d) acc += bW[hd * DHEAD + d] * vec[d];
      sbias[j] = acc;
    }
  }
}

// Kernel 1: 64x272 GEMM. Whb stored in PERMUTED row layout
// i = w*64 + mrow*4 + ni  <->  true col c = w*64 + ni*16 + mrow
// (consistent with aggregate below). Extra tile gives s1g/s2g directly.
// A staged to LDS once (fp32->bf16); barrier-free K-loop; B direct
// global->VGPR from L2-resident fragment-major Wt2.
__global__ __launch_bounds__(256) void gemm_fused(
    const float* __restrict__ h, const unsigned short* __restrict__ Wt2,
    const float* __restrict__ bW, const float* __restrict__ sbias,
    unsigned short* __restrict__ Whb, float* __restrict__ s1g,
    float* __restrict__ s2g) {
  __shared__ unsigned short As2[8 * 4 * 64 * 8];  // 32 KB, fragment-major
  const int tid = threadIdx.x;
  const int w = tid >> 6, lane = tid & 63;
  const int mrow = lane & 15, quad = lane >> 4;
  const int row0 = blockIdx.x * 64;

  {  // Stage A once: thread covers (row = w*16 + mrow, cols quad*8..+8) x 8 kt
    int grow = row0 + w * 16 + mrow;
    if (grow > NNODES - 1) grow = NNODES - 1;
    const float* hp = h + (size_t)grow * FEAT + quad * 8;
#pragma unroll
    for (int kt = 0; kt < 8; ++kt) {
      float4 v0 = *(const float4*)(hp + kt * 32);
      float4 v1 = *(const float4*)(hp + kt * 32 + 4);
      shortx8 a8;
      a8[0] = (short)f2bf(v0.x); a8[1] = (short)f2bf(v0.y);
      a8[2] = (short)f2bf(v0.z); a8[3] = (short)f2bf(v0.w);
      a8[4] = (short)f2bf(v1.x); a8[5] = (short)f2bf(v1.y);
      a8[6] = (short)f2bf(v1.z); a8[7] = (short)f2bf(v1.w);
      *(shortx8*)&As2[((kt * 4 + w) * 64 + lane) * 8] = a8;
    }
  }
  __syncthreads();

  floatx4 acc[4][4] = {};
  floatx4 acc_e[4] = {};  // extra tile (cols 256..271): s1/s2
#pragma unroll
  for (int kt = 0; kt < 8; ++kt) {
    shortx8 af[4], bfr[4], bfe;
#pragma unroll
    for (int ni = 0; ni < 4; ++ni) {
      int cgrp = w * 4 + ni;
      bfr[ni] = *(const shortx8*)&Wt2[((size_t)(cgrp * 8 + kt) * 64 + lane) * 8];
    }
    bfe = *(const shortx8*)&Wt2[((size_t)(16 * 8 + kt) * 64 + lane) * 8];
#pragma unroll
    for (int mi = 0; mi < 4; ++mi)
      af[mi] = *(const shortx8*)&As2[((kt * 4 + mi) * 64 + lane) * 8];
#pragma unroll
    for (int mi = 0; mi < 4; ++mi) {
#pragma unroll
      for (int ni = 0; ni < 4; ++ni)
        acc[mi][ni] = __builtin_amdgcn_mfma_f32_16x16x32_bf16(
            af[mi], bfr[ni], acc[mi][ni], 0, 0, 0);
      acc_e[mi] = __builtin_amdgcn_mfma_f32_16x16x32_bf16(
          af[mi], bfe, acc_e[mi], 0, 0, 0);
    }
  }

  // Epilogue. Normal cols: bias + pack 4 ni-values -> one ushort4 store
  // (permuted layout). Extra cols (wave 0 stores): s1g/s2g.
  float bias[4];
#pragma unroll
  for (int ni = 0; ni < 4; ++ni) bias[ni] = bW[w * 64 + ni * 16 + mrow];
#pragma unroll
  for (int mi = 0; mi < 4; ++mi) {
#pragma unroll
    for (int r = 0; r < 4; ++r) {
      int row = row0 + mi * 16 + quad * 4 + r;
      ushort4 pk;
      pk.x = f2bf(acc[mi][0][r] + bias[0]);
      pk.y = f2bf(acc[mi][1][r] + bias[1]);
      pk.z = f2bf(acc[mi][2][r] + bias[2]);
      pk.w = f2bf(acc[mi][3][r] + bias[3]);
      if (row < NNODES)
        *(ushort4*)&Whb[(size_t)row * CDIM + w * 64 + mrow * 4] = pk;
    }
  }
  if (w == 0) {
    float sb = sbias[mrow];  // lane's extra col j = mrow
#pragma unroll
    for (int mi = 0; mi < 4; ++mi) {
#pragma unroll
      for (int r = 0; r < 4; ++r) {
        int row = row0 + mi * 16 + quad * 4 + r;
        float val = acc_e[mi][r] + sb;
        if (row < NNODES) {
          if (mrow < 8) s1g[(size_t)row * NH + mrow] = val;
          else          s2g[(size_t)row * NH + (mrow - 8)] = val;
        }
      }
    }
  }
}

// Kernel 2: wave-per-node softmax + weighted gather (permuted Whb layout).
// Lane's 4 elements: j=0,1 -> head 2*(lane>>4); j=2,3 -> head 2*(lane>>4)+1.
__global__ __launch_bounds__(256) void aggregate(
    const unsigned short* __restrict__ Whb, const float* __restrict__ s1g,
    const float* __restrict__ s2g, const int* __restrict__ src,
    float* __restrict__ out) {
  __shared__ int srcs_s[4][DEG];
  __shared__ float sc_s[4][DEG * NH];
  int wave = threadIdx.x >> 6, lane = threadIdx.x & 63;
  int n = blockIdx.x * 4 + wave;
  if (lane < DEG) srcs_s[wave][lane] = src[(size_t)n * DEG + lane];
  __syncthreads();

  ushort4 vrows[DEG];
#pragma unroll
  for (int e = 0; e < DEG; ++e)
    vrows[e] = *(const ushort4*)&Whb[(size_t)srcs_s[wave][e] * CDIM + lane * 4];

  int hh7 = lane & 7;
  float s2v = s2g[(size_t)n * NH + hh7];  // a_bias folded in
#pragma unroll
  for (int p = 0; p < 2; ++p) {
    int i = lane + p * 64;
    int e = i >> 3;
    int s = srcs_s[wave][e];
    float sc = s1g[(size_t)s * NH + hh7] + s2v;
    sc_s[wave][i] = sc > 0.f ? sc : 0.2f * sc;  // leaky relu
  }
  __syncthreads();
  if (lane < 8) {
    float m = -1e30f;
#pragma unroll
    for (int e = 0; e < DEG; ++e) m = fmaxf(m, sc_s[wave][e * 8 + lane]);
    float sum = 0.f;
#pragma unroll
    for (int e = 0; e < DEG; ++e) {
      float ex = __expf(sc_s[wave][e * 8 + lane] - m);
      sc_s[wave][e * 8 + lane] = ex;
      sum += ex;
    }
    float inv = 1.f / sum;
#pragma unroll
    for (int e = 0; e < DEG; ++e) sc_s[wave][e * 8 + lane] *= inv;
  }
  __syncthreads();

  int m16 = lane & 15, wq = lane >> 4;
  int hA = wq * 2, hB = wq * 2 + 1;
  float ax = 0.f, ay = 0.f, az = 0.f, aw = 0.f;
#pragma unroll
  for (int e = 0; e < DEG; ++e) {
    float wA = sc_s[wave][e * 8 + hA];
    float wB = sc_s[wave][e * 8 + hB];
    ushort4 v = vrows[e];
    ax += wA * bf2f(v.x);
    ay += wA * bf2f(v.y);
    az += wB * bf2f(v.z);
    aw += wB * bf2f(v.w);
  }
  // true cols: w*64 + j*16 + m16
  size_t base = (size_t)n * CDIM + wq * 64 + m16;
  __builtin_nontemporal_store(ax, &out[base]);
  __builtin_nontemporal_store(ay, &out[base + 16]);
  __builtin_nontemporal_store(az, &out[base + 32]);
  __builtin_nontemporal_store(aw, &out[base + 48]);
}

extern "C" void kernel_launch(void* const* d_in, const int* in_sizes, int n_in,
                              void* d_out, int out_size, void* d_ws, size_t ws_size,
                              hipStream_t stream) {
  const float* h = (const float*)d_in[0];
  const float* W = (const float*)d_in[1];
  const float* bW = (const float*)d_in[2];
  const float* a_src = (const float*)d_in[3];
  const float* a_dst = (const float*)d_in[4];
  const float* a_bias = (const float*)d_in[5];
  const int* src = (const int*)d_in[6];
  // d_in[7] (dst) unused: dst = repeat(arange(N), DEG) structurally.
  float* out = (float*)d_out;

  unsigned short* Whb = (unsigned short*)d_ws;          // [N][256] bf16, 25.6 MB
  unsigned short* Wt2 = Whb + (size_t)NNODES * CDIM;    // 17*4096 bf16, 139 KB
  float* s1g = (float*)(Wt2 + 17 * 4096);               // [N][8] fp32, 1.6 MB
  float* s2g = s1g + (size_t)NNODES * NH;               // [N][8] fp32, 1.6 MB
  float* sbias = s2g + (size_t)NNODES * NH;             // 16 floats

  convert_wt<<<69, 256, 0, stream>>>(W, bW, a_src, a_dst, a_bias, Wt2, sbias);
  gemm_fused<<<(NNODES + 63) / 64, 256, 0, stream>>>(h, Wt2, bW, sbias, Whb,
                                                     s1g, s2g);
  aggregate<<<NNODES / 4, 256, 0, stream>>>(Whb, s1g, s2g, src, out);
}